// Round 7
// baseline (862.314 us; speedup 1.0000x reference)
//
#include <hip/hip_runtime.h>
#include <cstdint>
#include <cstddef>

#define B_   8
#define LQ_  2048
#define LK_  2048

typedef __attribute__((ext_vector_type(8))) __bf16 bf16x8;
typedef __attribute__((ext_vector_type(4))) float f32x4;
typedef __attribute__((ext_vector_type(8))) unsigned short ushortx8;

__device__ __forceinline__ unsigned short f2bf(float f) {
  unsigned u = __builtin_bit_cast(unsigned, f);
  u = u + 0x7fffu + ((u >> 16) & 1u);  // round-to-nearest-even
  return (unsigned short)(u >> 16);
}
__device__ __forceinline__ float bf2f(unsigned short h) {
  unsigned u = ((unsigned)h) << 16;
  return __builtin_bit_cast(float, u);
}

__device__ __forceinline__ void gld_lds16(const void* g, void* l) {
  __builtin_amdgcn_global_load_lds((__attribute__((address_space(1))) void*)(void*)g,
                                   (__attribute__((address_space(3))) void*)l, 16, 0, 0);
}

// ------------- flat cast fp32 -> bf16: queries + keys(row-clamped) + W_q -------------
__global__ __launch_bounds__(256) void cast3_bf16_kernel(
    const float* __restrict__ q, unsigned short* __restrict__ qo,
    const float* __restrict__ k, unsigned short* __restrict__ ko,
    const float* __restrict__ w, unsigned short* __restrict__ wo,
    const int* __restrict__ vlp) {
  int bb = (int)blockIdx.x;
  const float* in;
  unsigned short* out;
  if (bb < 8192) {
    in = q; out = qo;
  } else if (bb < 16384) {
    bb -= 8192;
    in = k; out = ko;
    int batch = bb >> 10;            // 1024 blocks per batch (2048x1024 elems)
    int row = (bb & 1023) * 2;       // 2 rows per block
    int vl = vlp[batch];
    if (row >= ((vl + 255) & ~255)) return;   // GEMM1' m-grain is 256
  } else {
    bb -= 16384;
    in = w; out = wo;
  }
  size_t i = ((size_t)bb * 256 + threadIdx.x) * 8;
  float4 a = *(const float4*)(in + i);
  float4 b = *(const float4*)(in + i + 4);
  ushortx8 o;
  o[0] = f2bf(a.x); o[1] = f2bf(a.y); o[2] = f2bf(a.z); o[3] = f2bf(a.w);
  o[4] = f2bf(b.x); o[5] = f2bf(b.y); o[6] = f2bf(b.z); o[7] = f2bf(b.w);
  *(ushortx8*)(out + i) = o;
}

// ====== 256x128 GEMM: 4 waves, per-wave 128x64, BK=32, ring-2 (48 KB), 3 blocks/CU ======
// C[M,N] = A[M,K] @ B[N,K]^T.  256 thr / 4 waves (2M x 2N), per-wave output 128x64.
// Per-busy-CU throughput of this geometry is ~47% matrix peak (measured r6); this
// round converts DILUTION into time: 48 KB LDS -> 3 blocks/CU (768 slots) makes
// GEMM2 (544 alive tiles) and GEMM1' (288) single-round, and gives GEMM3's long-vl
// pole blocks mostly-solo CU time after short partners finish.
// Ring-2 schedule per K-tile t: stage tile t+1 into slot (t+1)&1 (6 gld_lds) |
// ds_read 12 frags from slot t&1 | lgkm(0) | setprio 32 MFMA | vmcnt(0) | barrier.
// Loads get the whole MFMA phase (~2000 cyc) to land -> the drain is cheap; ring-3's
// extra depth only matters when latency > one K-tile (it isn't).
// Hazard: stage(t+1) targets the slot of tile t-1, whose ds_reads completed before
// the end-of-(t-1) barrier (lgkm(0) precedes MFMA). Same verified geometry as r0-r6:
// rowpair layout [*/2][64], 16B-chunk XOR swizzle pos = c ^ (p&7), 0 bank conflicts.
// Grid: 1-D z-inner (idx&7); n-tile rotated by batch. OUTM: 0 bf16, 1 bf16*scale,
// 2 fp32. SKIPN/SKIPM: cull n0/m0 >= vl. CLAMPK: K-loop to round64(vl).
template <int OUTM, int SKIPN, int SKIPM, int CLAMPK>
__global__ __launch_bounds__(256, 3) void gemm256x128_kernel(
    const unsigned short* __restrict__ A, const unsigned short* __restrict__ B,
    void* __restrict__ Cp, int M, int N, int K,
    long a_bstride, long b_bstride, long c_bstride, float scale,
    const int* __restrict__ vlp, int lognx) {
  __shared__ unsigned short lds[2][128 * 64 + 64 * 64];  // [ring][A:8192 | B:4096]

  const int tid = threadIdx.x;
  const int wid = tid >> 6;
  const int lane = tid & 63;
  const int lane15 = lane & 15;
  const int lhalf = lane >> 4;

  // ---- 1-D z-inner grid decode ----
  const int idx = (int)blockIdx.x;
  const int z = idx & 7;
  const int rest = idx >> 3;
  const int nxm = (1 << lognx) - 1;
  const int xt = rest & nxm;
  const int yt = rest >> lognx;
  const int nt = (xt + 2 * z) & nxm;  // batch-rotated n-tile
  const int m0 = yt * 256;
  const int n0 = nt * 128;

  int vl = K;
  if constexpr (SKIPN || SKIPM || CLAMPK) vl = vlp[z];
  if constexpr (SKIPN) {
    if (n0 >= vl) return;
  }
  if constexpr (SKIPM) {
    if (m0 >= vl) return;
  }
  int kEnd = K;
  if constexpr (CLAMPK) {
    int ke = (vl + 63) & ~63;
    kEnd = ke < K ? ke : K;
  }
  const int nKt = kEnd >> 5;  // K-tiles of 32; >= 2 (kEnd >= 64)

  const unsigned short* Ab = A + (size_t)z * a_bstride;
  const unsigned short* Bb = B + (size_t)z * b_bstride;

  // ---- staging precompute: A 1024 chunks (4/thr), B 512 chunks (2/thr) ----
  // chunk blk: p=blk>>3 (rowpair), c=(blk&7)^(p&7): src row=2p+(c>>2),
  // src col=(c&3)*8, LDS dst=blk*16B (within operand region).
  int srA[4], scA[4], sdA[4];
#pragma unroll
  for (int j = 0; j < 4; ++j) {
    int blk = (wid * 4 + j) * 64 + lane;  // wave-uniform base + lane (gld_lds req)
    int p = blk >> 3;
    int c = (blk & 7) ^ (p & 7);
    srA[j] = m0 + 2 * p + (c >> 2);
    scA[j] = (c & 3) * 8;
    sdA[j] = blk * 8;
  }
  int srB[2], scB[2], sdB[2];
#pragma unroll
  for (int j = 0; j < 2; ++j) {
    int blk = (wid * 2 + j) * 64 + lane;
    int p = blk >> 3;
    int c = (blk & 7) ^ (p & 7);
    srB[j] = n0 + 2 * p + (c >> 2);
    scB[j] = (c & 3) * 8;
    sdB[j] = 8192 + blk * 8;
  }

  // ---- read precompute (wave 2M x 2N -> 128x64 each) ----
  const int om = (wid & 1) * 128;  // wave M origin in tile
  const int on = (wid >> 1) * 64;  // wave N origin in tile
  const int swz8 = ((((lane15 & 1) << 2) + lhalf) ^ ((lane15 >> 1) & 7)) << 3;
  const int aBase = ((om >> 1) + (lane15 >> 1)) * 64 + swz8;
  const int bBase = 8192 + ((on >> 1) + (lane15 >> 1)) * 64 + swz8;

  f32x4 acc[8][4];
#pragma unroll
  for (int f = 0; f < 8; ++f)
#pragma unroll
    for (int g = 0; g < 4; ++g) acc[f][g] = (f32x4){0.f, 0.f, 0.f, 0.f};

#define STAGE_TILE(T, S)                                                        \
  {                                                                             \
    const int kc_ = (T) * 32;                                                   \
    _Pragma("unroll")                                                           \
    for (int j = 0; j < 4; ++j)                                                 \
      gld_lds16(Ab + (size_t)srA[j] * K + (kc_ + scA[j]), &lds[S][sdA[j]]);     \
    _Pragma("unroll")                                                           \
    for (int j = 0; j < 2; ++j)                                                 \
      gld_lds16(Bb + (size_t)srB[j] * K + (kc_ + scB[j]), &lds[S][sdB[j]]);     \
  }

  // ---- prologue: stage kt0 into slot 0 ----
  STAGE_TILE(0, 0);
  asm volatile("s_waitcnt vmcnt(0)" ::: "memory");
  __builtin_amdgcn_s_barrier();

  for (int t = 0; t < nKt; ++t) {
    const unsigned short* lcur = &lds[t & 1][0];
    // stage next tile first (vmem), then ds_reads (lgkm) — independent counters
    if (t + 1 < nKt) STAGE_TILE(t + 1, (t + 1) & 1);

    bf16x8 a[8], b[4];
#pragma unroll
    for (int f = 0; f < 8; ++f) a[f] = *(const bf16x8*)&lcur[aBase + f * 512];
#pragma unroll
    for (int g = 0; g < 4; ++g) b[g] = *(const bf16x8*)&lcur[bBase + g * 512];
    asm volatile("s_waitcnt lgkmcnt(0)" ::: "memory");
    __builtin_amdgcn_sched_barrier(0);
    __builtin_amdgcn_s_setprio(1);
#pragma unroll
    for (int f = 0; f < 8; ++f)
#pragma unroll
      for (int g = 0; g < 4; ++g)
        acc[f][g] = __builtin_amdgcn_mfma_f32_16x16x32_bf16(a[f], b[g], acc[f][g], 0, 0, 0);
    __builtin_amdgcn_s_setprio(0);
    asm volatile("s_waitcnt vmcnt(0)" ::: "memory");  // next tile resident
    __builtin_amdgcn_s_barrier();
  }
#undef STAGE_TILE

  // ---- epilogue: C/D layout col=lane&15, row=(lane>>4)*4+reg ----
  const size_t boffC = (size_t)z * c_bstride;
#pragma unroll
  for (int f = 0; f < 8; ++f) {
    int row = m0 + om + f * 16 + lhalf * 4;
#pragma unroll
    for (int g = 0; g < 4; ++g) {
      int col = n0 + on + g * 16 + lane15;
#pragma unroll
      for (int r = 0; r < 4; ++r) {
        float v = acc[f][g][r];
        if constexpr (OUTM == 0) {
          ((unsigned short*)Cp + boffC)[(size_t)(row + r) * N + col] = f2bf(v);
        } else if constexpr (OUTM == 1) {
          ((unsigned short*)Cp + boffC)[(size_t)(row + r) * N + col] = f2bf(v * scale);
        } else {
          ((float*)Cp + boffC)[(size_t)(row + r) * N + col] = v;
        }
      }
    }
  }
}

// ========== fused transposeV + softmax (both depend only on GEMM2) ==========
// blocks [0,16384): valsT[b][v][s] = values[b][s][v] (bf16), s-tiles clamped to
//   round64(vl) (GEMM3 never reads beyond). decode idx = x + 32y + 2048z.
// blocks [16384,32768): row softmax with valid_len masking, in place on bf16
//   scores; cols [vl, round64(vl)) get exact 0 (GEMM3 CLAMPK read range).
__global__ __launch_bounds__(256) void vtrans_softmax_kernel(
    const float* __restrict__ vals, unsigned short* __restrict__ valsT,
    unsigned short* __restrict__ scores, const int* __restrict__ valid_lens) {
  __shared__ float smem[32 * 33];
  const int bb = (int)blockIdx.x;
  const int tid = threadIdx.x;

  if (bb < 16384) {
    // ---- transpose+cast part: fp32 [2048][1024] -> bf16 [1024][2048] ----
    const int z = bb >> 11;
    const int r0 = ((bb >> 5) & 63) * 32;
    const int kEnd = (valid_lens[z] + 63) & ~63;
    if (r0 >= kEnd) return;
    const int c0 = (bb & 31) * 32;
    const int tx = tid & 31, ty = tid >> 5;  // (32,8)
    const float* inb = vals + (size_t)z * 2048 * 1024;
    unsigned short* outb = valsT + (size_t)z * 1024 * 2048;
#pragma unroll
    for (int k = 0; k < 4; ++k) {
      int r = ty + k * 8;
      smem[r * 33 + tx] = inb[(size_t)(r0 + r) * 1024 + c0 + tx];
    }
    __syncthreads();
#pragma unroll
    for (int k = 0; k < 4; ++k) {
      int c = ty + k * 8;
      outb[(size_t)(c0 + c) * 2048 + r0 + tx] = f2bf(smem[tx * 33 + c]);
    }
    return;
  }

  // ---- softmax part ----
  const int row = bb - 16384;
  const int b = row >> 11;  // LQ = 2048
  const int vl = valid_lens[b];
  const int kEnd = (vl + 63) & ~63;
  unsigned short* rp = scores + (size_t)row * LK_;
  const int wid = tid >> 6, lane = tid & 63;
  float* sred = smem;

  const int cb = tid * 8;
  const bool act = cb < kEnd;
  ushortx8 h = {};
  if (act) h = *(const ushortx8*)(rp + cb);
  float x[8];
#pragma unroll
  for (int t = 0; t < 8; ++t) x[t] = bf2f(h[t]);

  float m = -3.4e38f;
#pragma unroll
  for (int t = 0; t < 8; ++t)
    if (cb + t < vl) m = fmaxf(m, x[t]);
#pragma unroll
  for (int off = 32; off >= 1; off >>= 1) m = fmaxf(m, __shfl_xor(m, off));
  if (lane == 0) sred[wid] = m;
  __syncthreads();
  m = fmaxf(fmaxf(sred[0], sred[1]), fmaxf(sred[2], sred[3]));
  __syncthreads();

  float e[8];
  float s = 0.f;
#pragma unroll
  for (int t = 0; t < 8; ++t) {
    e[t] = (cb + t < vl) ? __expf(x[t] - m) : 0.f;
    s += e[t];
  }
#pragma unroll
  for (int off = 32; off >= 1; off >>= 1) s += __shfl_xor(s, off);
  if (lane == 0) sred[wid] = s;
  __syncthreads();
  s = sred[0] + sred[1] + sred[2] + sred[3];
  float inv = 1.f / s;

  if (act) {
    ushortx8 o;
#pragma unroll
    for (int t = 0; t < 8; ++t) o[t] = f2bf(e[t] * inv);
    *(ushortx8*)(rp + cb) = o;
  }
}

extern "C" void kernel_launch(void* const* d_in, const int* in_sizes, int n_in,
                              void* d_out, int out_size, void* d_ws, size_t ws_size,
                              hipStream_t stream) {
  const float* queries = (const float*)d_in[0];    // [8,2048,1024]
  const float* keys = (const float*)d_in[1];       // [8,2048,1024]
  const float* values = (const float*)d_in[2];     // [8,2048,1024]
  const int* valid_lens = (const int*)d_in[3];     // [8]
  const float* W_q = (const float*)d_in[4];        // [1024,1024]
  float* out = (float*)d_out;                      // [8,2048,1024] fp32

  // Re-association: scores = Q @ (K @ W^T)^T — project KEYS (maskable), not queries.
  // ws layout (ushort elems), total 81M = 162 MiB:
  //   q_bf    [0, 16M)      queries bf16
  //   scores  [16M, 48M)
  //   keysP   [48M, 64M)    K@W^T bf16; dead after GEMM2 -> valsT aliases it
  //   w_bf    [64M, 65M)    W_q bf16 row-major (= B^T operand as-is)
  //   keys_bf [65M, 81M)
  unsigned short* ws = (unsigned short*)d_ws;
  const size_t M1 = (size_t)1024 * 1024;
  unsigned short* q_bf = ws;
  unsigned short* scores = ws + 16 * M1;
  unsigned short* keysP = ws + 48 * M1;
  unsigned short* valsT = keysP;  // alias — transpose runs after GEMM2
  unsigned short* w_bf = ws + 64 * M1;
  unsigned short* keys_bf = ws + 65 * M1;

  // casts: queries + keys(row-clamped to round256(vl)) + W_q
  cast3_bf16_kernel<<<dim3(16896), 256, 0, stream>>>(
      queries, q_bf, keys, keys_bf, W_q, w_bf, valid_lens);
  // GEMM1': keysP[b] = keys_bf[b] @ W_q^T -> bf16 [2048,1024]; skip m-tiles >= vl
  // grid: 8y(256-tiles) x 8x(128-tiles) x 8z, z-inner; ~288 alive on 768 slots
  gemm256x128_kernel<0, 0, 1, 0><<<dim3(8 * 8 * 8), 256, 0, stream>>>(
      keys_bf, w_bf, keysP, 2048, 1024, 1024,
      (long)2048 * 1024, 0, (long)2048 * 1024, 1.f, valid_lens, 3);
  // GEMM2': scores = q_bf @ keysP^T / 32 -> bf16 [8][2048][2048]; cull masked n-tiles
  // grid: 8y x 16x x 8z, z-inner; ~544 alive on 768 slots -> single round
  gemm256x128_kernel<1, 1, 0, 0><<<dim3(8 * 16 * 8), 256, 0, stream>>>(
      q_bf, keysP, scores, 2048, 2048, 1024,
      (long)2048 * 1024, (long)2048 * 1024, (long)2048 * 2048, 0.03125f, valid_lens, 4);
  // fused: valsT transpose (clamped) + masked softmax — one launch, both post-GEMM2
  vtrans_softmax_kernel<<<dim3(32768), 256, 0, stream>>>(
      values, valsT, scores, valid_lens);
  // GEMM3: out = attn @ values (fp32 epilogue); K-loop clamped to valid_len
  // grid: 8y x 8x x 8z, z-inner (512 jobs on 768 slots; long-vl blocks finish solo)
  gemm256x128_kernel<2, 0, 0, 1><<<dim3(8 * 8 * 8), 256, 0, stream>>>(
      scores, valsT, out, 2048, 1024, 2048,
      (long)2048 * 2048, (long)1024 * 2048, (long)2048 * 1024, 1.f, valid_lens, 3);
}

// Round 8
// 366.548 us; speedup vs baseline: 2.3525x; 2.3525x over previous
//
#include <hip/hip_runtime.h>
#include <cstdint>
#include <cstddef>

#define B_   8
#define LQ_  2048
#define LK_  2048

typedef __attribute__((ext_vector_type(8))) __bf16 bf16x8;
typedef __attribute__((ext_vector_type(4))) float f32x4;
typedef __attribute__((ext_vector_type(8))) unsigned short ushortx8;

__device__ __forceinline__ unsigned short f2bf(float f) {
  unsigned u = __builtin_bit_cast(unsigned, f);
  u = u + 0x7fffu + ((u >> 16) & 1u);  // round-to-nearest-even
  return (unsigned short)(u >> 16);
}
__device__ __forceinline__ float bf2f(unsigned short h) {
  unsigned u = ((unsigned)h) << 16;
  return __builtin_bit_cast(float, u);
}

__device__ __forceinline__ void gld_lds16(const void* g, void* l) {
  __builtin_amdgcn_global_load_lds((__attribute__((address_space(1))) void*)(void*)g,
                                   (__attribute__((address_space(3))) void*)l, 16, 0, 0);
}

// ------------- cast fp32 -> bf16: keys (row-clamped) + W_q only -------------
// (queries cast is fused into the GEMM1' launch as trailing blocks)
__global__ __launch_bounds__(256) void cast_kw_kernel(
    const float* __restrict__ k, unsigned short* __restrict__ ko,
    const float* __restrict__ w, unsigned short* __restrict__ wo,
    const int* __restrict__ vlp) {
  int bb = (int)blockIdx.x;
  const float* in;
  unsigned short* out;
  if (bb < 8192) {
    in = k; out = ko;
    int batch = bb >> 10;            // 1024 blocks per batch (2048x1024 elems)
    int row = (bb & 1023) * 2;       // 2 rows per block
    int vl = vlp[batch];
    if (row >= ((vl + 255) & ~255)) return;   // GEMM1' m-grain is 256
  } else {
    bb -= 8192;
    in = w; out = wo;
  }
  size_t i = ((size_t)bb * 256 + threadIdx.x) * 8;
  float4 a = *(const float4*)(in + i);
  float4 b = *(const float4*)(in + i + 4);
  ushortx8 o;
  o[0] = f2bf(a.x); o[1] = f2bf(a.y); o[2] = f2bf(a.z); o[3] = f2bf(a.w);
  o[4] = f2bf(b.x); o[5] = f2bf(b.y); o[6] = f2bf(b.z); o[7] = f2bf(b.w);
  *(ushortx8*)(out + i) = o;
}

// ====== 256x128 GEMM: 4 waves, per-wave 128x64, BK=32, ring-3, 2 blocks/CU ======
// EXACT r6 kernel (proven 70-73 us, 0 bank conflicts, no spill at
// __launch_bounds__(256,2): acc[8][4]=128 AGPR + ~100 VGPR fits the 256-reg
// budget; r7's (256,3) capped at ~170 and spilled acc -> 286 MB scratch writes).
// Ring-3 schedule per K-tile t: ds_read 12 frags | stage tile t+2 (6 gld_lds) |
//   lgkm(0) | setprio 32 MFMA | vmcnt(6 counted / 0 tail) | s_barrier.
// Hazard: stage(t+2) overwrites slot of tile t-1 (reads done before end-of-(t-1)
// barrier); vmcnt(6) leaves exactly t+2's 6 loads in flight -> t+1 resident.
// LDS layout: rowpair [*/2][64], 16B-chunk XOR swizzle pos = c ^ (p&7).
// QCAST: blocks with idx >= ngemm do a queries fp32->bf16 cast chunk instead
// (region-fused launch; GEMM1' has ~288 alive GEMM blocks on 512 slots, so the
// cast blocks backfill idle CUs and the separate dispatch disappears).
// OUTM: 0 bf16, 1 bf16*scale, 2 fp32. SKIPN/SKIPM: cull n0/m0 >= vl.
// CLAMPK: clamp K-loop to round64(vl).
template <int OUTM, int SKIPN, int SKIPM, int CLAMPK, int QCAST>
__global__ __launch_bounds__(256, 2) void gemm256x128_kernel(
    const unsigned short* __restrict__ A, const unsigned short* __restrict__ B,
    void* __restrict__ Cp, int M, int N, int K,
    long a_bstride, long b_bstride, long c_bstride, float scale,
    const int* __restrict__ vlp, int lognx,
    const float* __restrict__ qf, unsigned short* __restrict__ qbf, int ngemm) {
  __shared__ unsigned short lds[3][128 * 64 + 64 * 64];  // [ring][A:8192 | B:4096]

  const int tid = threadIdx.x;

  if constexpr (QCAST) {
    if ((int)blockIdx.x >= ngemm) {
      size_t i = ((size_t)((int)blockIdx.x - ngemm) * 256 + tid) * 8;
      float4 a = *(const float4*)(qf + i);
      float4 b = *(const float4*)(qf + i + 4);
      ushortx8 o;
      o[0] = f2bf(a.x); o[1] = f2bf(a.y); o[2] = f2bf(a.z); o[3] = f2bf(a.w);
      o[4] = f2bf(b.x); o[5] = f2bf(b.y); o[6] = f2bf(b.z); o[7] = f2bf(b.w);
      *(ushortx8*)(qbf + i) = o;
      return;
    }
  }

  const int wid = tid >> 6;
  const int lane = tid & 63;
  const int lane15 = lane & 15;
  const int lhalf = lane >> 4;

  // ---- 1-D z-inner grid decode ----
  const int idx = (int)blockIdx.x;
  const int z = idx & 7;
  const int rest = idx >> 3;
  const int nxm = (1 << lognx) - 1;
  const int xt = rest & nxm;
  const int yt = rest >> lognx;
  const int nt = (xt + 2 * z) & nxm;  // batch-rotated n-tile
  const int m0 = yt * 256;
  const int n0 = nt * 128;

  int vl = K;
  if constexpr (SKIPN || SKIPM || CLAMPK) vl = vlp[z];
  if constexpr (SKIPN) {
    if (n0 >= vl) return;
  }
  if constexpr (SKIPM) {
    if (m0 >= vl) return;
  }
  int kEnd = K;
  if constexpr (CLAMPK) {
    int ke = (vl + 63) & ~63;
    kEnd = ke < K ? ke : K;
  }
  const int nKt = kEnd >> 5;  // K-tiles of 32; >= 2 (kEnd >= 64)

  const unsigned short* Ab = A + (size_t)z * a_bstride;
  const unsigned short* Bb = B + (size_t)z * b_bstride;

  // ---- staging precompute: A 1024 chunks (4/thr), B 512 chunks (2/thr) ----
  // chunk blk: p=blk>>3 (rowpair), c=(blk&7)^(p&7): src row=2p+(c>>2),
  // src col=(c&3)*8, LDS dst=blk*16B (within operand region).
  int srA[4], scA[4], sdA[4];
#pragma unroll
  for (int j = 0; j < 4; ++j) {
    int blk = (wid * 4 + j) * 64 + lane;  // wave-uniform base + lane (gld_lds req)
    int p = blk >> 3;
    int c = (blk & 7) ^ (p & 7);
    srA[j] = m0 + 2 * p + (c >> 2);
    scA[j] = (c & 3) * 8;
    sdA[j] = blk * 8;
  }
  int srB[2], scB[2], sdB[2];
#pragma unroll
  for (int j = 0; j < 2; ++j) {
    int blk = (wid * 2 + j) * 64 + lane;
    int p = blk >> 3;
    int c = (blk & 7) ^ (p & 7);
    srB[j] = n0 + 2 * p + (c >> 2);
    scB[j] = (c & 3) * 8;
    sdB[j] = 8192 + blk * 8;
  }

  // ---- read precompute (wave 2M x 2N -> 128x64 each) ----
  const int om = (wid & 1) * 128;  // wave M origin in tile
  const int on = (wid >> 1) * 64;  // wave N origin in tile
  const int swz8 = ((((lane15 & 1) << 2) + lhalf) ^ ((lane15 >> 1) & 7)) << 3;
  const int aBase = ((om >> 1) + (lane15 >> 1)) * 64 + swz8;
  const int bBase = 8192 + ((on >> 1) + (lane15 >> 1)) * 64 + swz8;

  f32x4 acc[8][4];
#pragma unroll
  for (int f = 0; f < 8; ++f)
#pragma unroll
    for (int g = 0; g < 4; ++g) acc[f][g] = (f32x4){0.f, 0.f, 0.f, 0.f};

#define STAGE_TILE(T, S)                                                        \
  {                                                                             \
    const int kc_ = (T) * 32;                                                   \
    _Pragma("unroll")                                                           \
    for (int j = 0; j < 4; ++j)                                                 \
      gld_lds16(Ab + (size_t)srA[j] * K + (kc_ + scA[j]), &lds[S][sdA[j]]);     \
    _Pragma("unroll")                                                           \
    for (int j = 0; j < 2; ++j)                                                 \
      gld_lds16(Bb + (size_t)srB[j] * K + (kc_ + scB[j]), &lds[S][sdB[j]]);     \
  }

  // ---- prologue: stage kt0 (slot0), kt1 (slot1); vmcnt(6) -> kt0 resident ----
  STAGE_TILE(0, 0);
  STAGE_TILE(1, 1);
  asm volatile("s_waitcnt vmcnt(6)" ::: "memory");
  __builtin_amdgcn_s_barrier();

  int cs = 0;  // ring slot of tile t
  for (int t = 0; t < nKt; ++t) {
    const unsigned short* lcur = &lds[cs][0];
    const bool st = (t + 2) < nKt;
    const int ss = cs == 0 ? 2 : cs - 1;  // slot of t+2 == slot of t-1

    bf16x8 a[8], b[4];
#pragma unroll
    for (int f = 0; f < 8; ++f) a[f] = *(const bf16x8*)&lcur[aBase + f * 512];
#pragma unroll
    for (int g = 0; g < 4; ++g) b[g] = *(const bf16x8*)&lcur[bBase + g * 512];
    if (st) STAGE_TILE(t + 2, ss);
    asm volatile("s_waitcnt lgkmcnt(0)" ::: "memory");
    __builtin_amdgcn_sched_barrier(0);
    __builtin_amdgcn_s_setprio(1);
#pragma unroll
    for (int f = 0; f < 8; ++f)
#pragma unroll
      for (int g = 0; g < 4; ++g)
        acc[f][g] = __builtin_amdgcn_mfma_f32_16x16x32_bf16(a[f], b[g], acc[f][g], 0, 0, 0);
    __builtin_amdgcn_s_setprio(0);
    if (st)
      asm volatile("s_waitcnt vmcnt(6)" ::: "memory");  // t+1 resident; t+2 in flight
    else
      asm volatile("s_waitcnt vmcnt(0)" ::: "memory");  // tail drain
    __builtin_amdgcn_s_barrier();
    cs = cs == 2 ? 0 : cs + 1;
  }
#undef STAGE_TILE

  // ---- epilogue: C/D layout col=lane&15, row=(lane>>4)*4+reg ----
  const size_t boffC = (size_t)z * c_bstride;
#pragma unroll
  for (int f = 0; f < 8; ++f) {
    int row = m0 + om + f * 16 + lhalf * 4;
#pragma unroll
    for (int g = 0; g < 4; ++g) {
      int col = n0 + on + g * 16 + lane15;
#pragma unroll
      for (int r = 0; r < 4; ++r) {
        float v = acc[f][g][r];
        if constexpr (OUTM == 0) {
          ((unsigned short*)Cp + boffC)[(size_t)(row + r) * N + col] = f2bf(v);
        } else if constexpr (OUTM == 1) {
          ((unsigned short*)Cp + boffC)[(size_t)(row + r) * N + col] = f2bf(v * scale);
        } else {
          ((float*)Cp + boffC)[(size_t)(row + r) * N + col] = v;
        }
      }
    }
  }
}

// ========== fused transposeV + softmax (both depend only on GEMM2) ==========
// blocks [0,16384): valsT[b][v][s] = values[b][s][v] (bf16), s-tiles clamped to
//   round64(vl) (GEMM3 never reads beyond). decode idx = x + 32y + 2048z.
// blocks [16384,32768): row softmax with valid_len masking, in place on bf16
//   scores; cols [vl, round64(vl)) get exact 0 (GEMM3 CLAMPK read range).
__global__ __launch_bounds__(256) void vtrans_softmax_kernel(
    const float* __restrict__ vals, unsigned short* __restrict__ valsT,
    unsigned short* __restrict__ scores, const int* __restrict__ valid_lens) {
  __shared__ float smem[32 * 33];
  const int bb = (int)blockIdx.x;
  const int tid = threadIdx.x;

  if (bb < 16384) {
    // ---- transpose+cast part: fp32 [2048][1024] -> bf16 [1024][2048] ----
    const int z = bb >> 11;
    const int r0 = ((bb >> 5) & 63) * 32;
    const int kEnd = (valid_lens[z] + 63) & ~63;
    if (r0 >= kEnd) return;
    const int c0 = (bb & 31) * 32;
    const int tx = tid & 31, ty = tid >> 5;  // (32,8)
    const float* inb = vals + (size_t)z * 2048 * 1024;
    unsigned short* outb = valsT + (size_t)z * 1024 * 2048;
#pragma unroll
    for (int k = 0; k < 4; ++k) {
      int r = ty + k * 8;
      smem[r * 33 + tx] = inb[(size_t)(r0 + r) * 1024 + c0 + tx];
    }
    __syncthreads();
#pragma unroll
    for (int k = 0; k < 4; ++k) {
      int c = ty + k * 8;
      outb[(size_t)(c0 + c) * 2048 + r0 + tx] = f2bf(smem[tx * 33 + c]);
    }
    return;
  }

  // ---- softmax part ----
  const int row = bb - 16384;
  const int b = row >> 11;  // LQ = 2048
  const int vl = valid_lens[b];
  const int kEnd = (vl + 63) & ~63;
  unsigned short* rp = scores + (size_t)row * LK_;
  const int wid = tid >> 6, lane = tid & 63;
  float* sred = smem;

  const int cb = tid * 8;
  const bool act = cb < kEnd;
  ushortx8 h = {};
  if (act) h = *(const ushortx8*)(rp + cb);
  float x[8];
#pragma unroll
  for (int t = 0; t < 8; ++t) x[t] = bf2f(h[t]);

  float m = -3.4e38f;
#pragma unroll
  for (int t = 0; t < 8; ++t)
    if (cb + t < vl) m = fmaxf(m, x[t]);
#pragma unroll
  for (int off = 32; off >= 1; off >>= 1) m = fmaxf(m, __shfl_xor(m, off));
  if (lane == 0) sred[wid] = m;
  __syncthreads();
  m = fmaxf(fmaxf(sred[0], sred[1]), fmaxf(sred[2], sred[3]));
  __syncthreads();

  float e[8];
  float s = 0.f;
#pragma unroll
  for (int t = 0; t < 8; ++t) {
    e[t] = (cb + t < vl) ? __expf(x[t] - m) : 0.f;
    s += e[t];
  }
#pragma unroll
  for (int off = 32; off >= 1; off >>= 1) s += __shfl_xor(s, off);
  if (lane == 0) sred[wid] = s;
  __syncthreads();
  s = sred[0] + sred[1] + sred[2] + sred[3];
  float inv = 1.f / s;

  if (act) {
    ushortx8 o;
#pragma unroll
    for (int t = 0; t < 8; ++t) o[t] = f2bf(e[t] * inv);
    *(ushortx8*)(rp + cb) = o;
  }
}

extern "C" void kernel_launch(void* const* d_in, const int* in_sizes, int n_in,
                              void* d_out, int out_size, void* d_ws, size_t ws_size,
                              hipStream_t stream) {
  const float* queries = (const float*)d_in[0];    // [8,2048,1024]
  const float* keys = (const float*)d_in[1];       // [8,2048,1024]
  const float* values = (const float*)d_in[2];     // [8,2048,1024]
  const int* valid_lens = (const int*)d_in[3];     // [8]
  const float* W_q = (const float*)d_in[4];        // [1024,1024]
  float* out = (float*)d_out;                      // [8,2048,1024] fp32

  // Re-association: scores = Q @ (K @ W^T)^T — project KEYS (maskable), not queries.
  // ws layout (ushort elems), total 81M = 162 MiB:
  //   q_bf    [0, 16M)      queries bf16
  //   scores  [16M, 48M)
  //   keysP   [48M, 64M)    K@W^T bf16; dead after GEMM2 -> valsT aliases it
  //   w_bf    [64M, 65M)    W_q bf16 row-major (= B^T operand as-is)
  //   keys_bf [65M, 81M)
  unsigned short* ws = (unsigned short*)d_ws;
  const size_t M1 = (size_t)1024 * 1024;
  unsigned short* q_bf = ws;
  unsigned short* scores = ws + 16 * M1;
  unsigned short* keysP = ws + 48 * M1;
  unsigned short* valsT = keysP;  // alias — transpose runs after GEMM2
  unsigned short* w_bf = ws + 64 * M1;
  unsigned short* keys_bf = ws + 65 * M1;

  // cast: keys (row-clamped to round256(vl)) + W_q. Queries cast is fused below.
  cast_kw_kernel<<<dim3(8704), 256, 0, stream>>>(
      keys, keys_bf, W_q, w_bf, valid_lens);
  // GEMM1': keysP[b] = keys_bf[b] @ W_q^T -> bf16 [2048,1024]; skip m-tiles >= vl.
  // Blocks [0,512): GEMM (8y x 8x x 8z, z-inner; ~288 alive on 512 slots).
  // Blocks [512,8704): queries fp32->bf16 cast backfilling the idle slots.
  gemm256x128_kernel<0, 0, 1, 0, 1><<<dim3(512 + 8192), 256, 0, stream>>>(
      keys_bf, w_bf, keysP, 2048, 1024, 1024,
      (long)2048 * 1024, 0, (long)2048 * 1024, 1.f, valid_lens, 3,
      queries, q_bf, 512);
  // GEMM2': scores = q_bf @ keysP^T / 32 -> bf16 [8][2048][2048]; cull masked n-tiles
  // grid: 8y x 16x x 8z, z-inner; ~544 alive on 512 slots
  gemm256x128_kernel<1, 1, 0, 0, 0><<<dim3(8 * 16 * 8), 256, 0, stream>>>(
      q_bf, keysP, scores, 2048, 2048, 1024,
      (long)2048 * 1024, (long)2048 * 1024, (long)2048 * 2048, 0.03125f, valid_lens, 4,
      nullptr, nullptr, 0);
  // fused: valsT transpose (clamped) + masked softmax — one launch, both post-GEMM2
  vtrans_softmax_kernel<<<dim3(32768), 256, 0, stream>>>(
      values, valsT, scores, valid_lens);
  // GEMM3: out = attn @ values (fp32 epilogue); K-loop clamped to valid_len
  // grid: 8y x 8x x 8z, z-inner (512 jobs on 512 slots, vl mixed)
  gemm256x128_kernel<2, 0, 0, 1, 0><<<dim3(8 * 8 * 8), 256, 0, stream>>>(
      scores, valsT, out, 2048, 1024, 2048,
      (long)2048 * 2048, (long)1024 * 2048, (long)2048 * 1024, 1.f, valid_lens, 3,
      nullptr, nullptr, 0);
}

// Round 9
// 366.388 us; speedup vs baseline: 2.3536x; 1.0004x over previous
//
#include <hip/hip_runtime.h>
#include <cstdint>
#include <cstddef>

#define B_   8
#define LQ_  2048
#define LK_  2048

typedef __attribute__((ext_vector_type(8))) __bf16 bf16x8;
typedef __attribute__((ext_vector_type(4))) float f32x4;
typedef __attribute__((ext_vector_type(8))) unsigned short ushortx8;

__device__ __forceinline__ unsigned short f2bf(float f) {
  unsigned u = __builtin_bit_cast(unsigned, f);
  u = u + 0x7fffu + ((u >> 16) & 1u);  // round-to-nearest-even
  return (unsigned short)(u >> 16);
}
__device__ __forceinline__ float bf2f(unsigned short h) {
  unsigned u = ((unsigned)h) << 16;
  return __builtin_bit_cast(float, u);
}

__device__ __forceinline__ void gld_lds16(const void* g, void* l) {
  __builtin_amdgcn_global_load_lds((__attribute__((address_space(1))) void*)(void*)g,
                                   (__attribute__((address_space(3))) void*)l, 16, 0, 0);
}

// ------------- cast fp32 -> bf16: keys (row-clamped) + W_q only -------------
// (queries cast is fused into the GEMM1' launch as trailing blocks)
__global__ __launch_bounds__(256) void cast_kw_kernel(
    const float* __restrict__ k, unsigned short* __restrict__ ko,
    const float* __restrict__ w, unsigned short* __restrict__ wo,
    const int* __restrict__ vlp) {
  int bb = (int)blockIdx.x;
  const float* in;
  unsigned short* out;
  if (bb < 8192) {
    in = k; out = ko;
    int batch = bb >> 10;            // 1024 blocks per batch (2048x1024 elems)
    int row = (bb & 1023) * 2;       // 2 rows per block
    int vl = vlp[batch];
    if (row >= ((vl + 255) & ~255)) return;   // GEMM1' m-grain is 256
  } else {
    bb -= 8192;
    in = w; out = wo;
  }
  size_t i = ((size_t)bb * 256 + threadIdx.x) * 8;
  float4 a = *(const float4*)(in + i);
  float4 b = *(const float4*)(in + i + 4);
  ushortx8 o;
  o[0] = f2bf(a.x); o[1] = f2bf(a.y); o[2] = f2bf(a.z); o[3] = f2bf(a.w);
  o[4] = f2bf(b.x); o[5] = f2bf(b.y); o[6] = f2bf(b.z); o[7] = f2bf(b.w);
  *(ushortx8*)(out + i) = o;
}

// ====== 256x128 GEMM: 4 waves, per-wave 128x64, BK=32, ring-2 (48 KB), 3 blocks/CU ======
// Changes vs r8 (both evidence-backed, see m141/m190 in the guide):
//  (1) UNPINNED K-loop: no setprio, no lgkm(0), no sched_barrier(0). The compiler
//      emits fine-grained lgkmcnt(N) between ds_read and dependent MFMA, so MFMAs
//      overlap later reads (r2-r8 pinned a full LDS drain before any MFMA —
//      serializing the LDS pipe (~1430 cyc/K-tile/CU) with the MFMA pipe
//      (~1240 cyc): measured 2655 = their SUM).
//  (2) ring-2 -> 48 KB LDS -> 3 blocks/CU at __launch_bounds__(256,2): VGPR stays
//      usage-driven (~104; 3 waves/SIMD x 104 = 312 <= 512 regs). r7's failure was
//      the (256,3) BOUND capping VGPR at ~170 -> acc spill; this config has no cap
//      pressure. 768 block slots: GEMM2 (544 alive) single-round; GEMM3's 64
//      pole blocks spread 3-deep instead of pairing on 2-slot CUs.
// Hazards (unchanged semantics): stage(t+1) at loop top targets slot of tile t-1,
// whose ds_reads completed before iter-(t-1)'s barrier (reads feed MFMAs; lgkm
// waits are data-dependence-enforced; wave reaches barrier only after MFMA issue).
// The end-of-iter vmcnt(0) asm ("memory" clobber) is the compiler fence that
// keeps next-iter ds_reads from hoisting above the residency wait.
// LDS layout: rowpair [*/2][64], 16B-chunk XOR swizzle pos = c ^ (p&7) (0-conflict).
// QCAST: blocks idx >= ngemm do a queries fp32->bf16 cast chunk (backfill fusion).
// OUTM: 0 bf16, 1 bf16*scale, 2 fp32. SKIPN/SKIPM: cull n0/m0 >= vl.
// CLAMPK: clamp K-loop to round64(vl).
template <int OUTM, int SKIPN, int SKIPM, int CLAMPK, int QCAST>
__global__ __launch_bounds__(256, 2) void gemm256x128_kernel(
    const unsigned short* __restrict__ A, const unsigned short* __restrict__ B,
    void* __restrict__ Cp, int M, int N, int K,
    long a_bstride, long b_bstride, long c_bstride, float scale,
    const int* __restrict__ vlp, int lognx,
    const float* __restrict__ qf, unsigned short* __restrict__ qbf, int ngemm) {
  __shared__ unsigned short lds[2][128 * 64 + 64 * 64];  // [ring][A:8192 | B:4096]

  const int tid = threadIdx.x;

  if constexpr (QCAST) {
    if ((int)blockIdx.x >= ngemm) {
      size_t i = ((size_t)((int)blockIdx.x - ngemm) * 256 + tid) * 8;
      float4 a = *(const float4*)(qf + i);
      float4 b = *(const float4*)(qf + i + 4);
      ushortx8 o;
      o[0] = f2bf(a.x); o[1] = f2bf(a.y); o[2] = f2bf(a.z); o[3] = f2bf(a.w);
      o[4] = f2bf(b.x); o[5] = f2bf(b.y); o[6] = f2bf(b.z); o[7] = f2bf(b.w);
      *(ushortx8*)(qbf + i) = o;
      return;
    }
  }

  const int wid = tid >> 6;
  const int lane = tid & 63;
  const int lane15 = lane & 15;
  const int lhalf = lane >> 4;

  // ---- 1-D z-inner grid decode ----
  const int idx = (int)blockIdx.x;
  const int z = idx & 7;
  const int rest = idx >> 3;
  const int nxm = (1 << lognx) - 1;
  const int xt = rest & nxm;
  const int yt = rest >> lognx;
  const int nt = (xt + 2 * z) & nxm;  // batch-rotated n-tile
  const int m0 = yt * 256;
  const int n0 = nt * 128;

  int vl = K;
  if constexpr (SKIPN || SKIPM || CLAMPK) vl = vlp[z];
  if constexpr (SKIPN) {
    if (n0 >= vl) return;
  }
  if constexpr (SKIPM) {
    if (m0 >= vl) return;
  }
  int kEnd = K;
  if constexpr (CLAMPK) {
    int ke = (vl + 63) & ~63;
    kEnd = ke < K ? ke : K;
  }
  const int nKt = kEnd >> 5;  // K-tiles of 32; >= 2 (kEnd >= 64)

  const unsigned short* Ab = A + (size_t)z * a_bstride;
  const unsigned short* Bb = B + (size_t)z * b_bstride;

  // ---- staging precompute: A 1024 chunks (4/thr), B 512 chunks (2/thr) ----
  // chunk blk: p=blk>>3 (rowpair), c=(blk&7)^(p&7): src row=2p+(c>>2),
  // src col=(c&3)*8, LDS dst=blk*16B (within operand region).
  int srA[4], scA[4], sdA[4];
#pragma unroll
  for (int j = 0; j < 4; ++j) {
    int blk = (wid * 4 + j) * 64 + lane;  // wave-uniform base + lane (gld_lds req)
    int p = blk >> 3;
    int c = (blk & 7) ^ (p & 7);
    srA[j] = m0 + 2 * p + (c >> 2);
    scA[j] = (c & 3) * 8;
    sdA[j] = blk * 8;
  }
  int srB[2], scB[2], sdB[2];
#pragma unroll
  for (int j = 0; j < 2; ++j) {
    int blk = (wid * 2 + j) * 64 + lane;
    int p = blk >> 3;
    int c = (blk & 7) ^ (p & 7);
    srB[j] = n0 + 2 * p + (c >> 2);
    scB[j] = (c & 3) * 8;
    sdB[j] = 8192 + blk * 8;
  }

  // ---- read precompute (wave 2M x 2N -> 128x64 each) ----
  const int om = (wid & 1) * 128;  // wave M origin in tile
  const int on = (wid >> 1) * 64;  // wave N origin in tile
  const int swz8 = ((((lane15 & 1) << 2) + lhalf) ^ ((lane15 >> 1) & 7)) << 3;
  const int aBase = ((om >> 1) + (lane15 >> 1)) * 64 + swz8;
  const int bBase = 8192 + ((on >> 1) + (lane15 >> 1)) * 64 + swz8;

  f32x4 acc[8][4];
#pragma unroll
  for (int f = 0; f < 8; ++f)
#pragma unroll
    for (int g = 0; g < 4; ++g) acc[f][g] = (f32x4){0.f, 0.f, 0.f, 0.f};

#define STAGE_TILE(T, S)                                                        \
  {                                                                             \
    const int kc_ = (T) * 32;                                                   \
    _Pragma("unroll")                                                           \
    for (int j = 0; j < 4; ++j)                                                 \
      gld_lds16(Ab + (size_t)srA[j] * K + (kc_ + scA[j]), &lds[S][sdA[j]]);     \
    _Pragma("unroll")                                                           \
    for (int j = 0; j < 2; ++j)                                                 \
      gld_lds16(Bb + (size_t)srB[j] * K + (kc_ + scB[j]), &lds[S][sdB[j]]);     \
  }

  // ---- prologue: stage kt0 into slot 0 ----
  STAGE_TILE(0, 0);
  asm volatile("s_waitcnt vmcnt(0)" ::: "memory");
  __builtin_amdgcn_s_barrier();

  for (int t = 0; t < nKt; ++t) {
    const unsigned short* lcur = &lds[t & 1][0];
    // issue next tile's staging first (vmem counter); lands under this tile's body
    if (t + 1 < nKt) STAGE_TILE(t + 1, (t + 1) & 1);

    bf16x8 a[8], b[4];
#pragma unroll
    for (int f = 0; f < 8; ++f) a[f] = *(const bf16x8*)&lcur[aBase + f * 512];
#pragma unroll
    for (int g = 0; g < 4; ++g) b[g] = *(const bf16x8*)&lcur[bBase + g * 512];
    // UNPINNED: compiler emits fine-grained lgkmcnt between reads and MFMAs,
    // overlapping LDS-read latency with MFMA issue (m141 lesson).
#pragma unroll
    for (int f = 0; f < 8; ++f)
#pragma unroll
      for (int g = 0; g < 4; ++g)
        acc[f][g] = __builtin_amdgcn_mfma_f32_16x16x32_bf16(a[f], b[g], acc[f][g], 0, 0, 0);
    asm volatile("s_waitcnt vmcnt(0)" ::: "memory");  // next tile resident (fence)
    __builtin_amdgcn_s_barrier();
  }
#undef STAGE_TILE

  // ---- epilogue: C/D layout col=lane&15, row=(lane>>4)*4+reg ----
  const size_t boffC = (size_t)z * c_bstride;
#pragma unroll
  for (int f = 0; f < 8; ++f) {
    int row = m0 + om + f * 16 + lhalf * 4;
#pragma unroll
    for (int g = 0; g < 4; ++g) {
      int col = n0 + on + g * 16 + lane15;
#pragma unroll
      for (int r = 0; r < 4; ++r) {
        float v = acc[f][g][r];
        if constexpr (OUTM == 0) {
          ((unsigned short*)Cp + boffC)[(size_t)(row + r) * N + col] = f2bf(v);
        } else if constexpr (OUTM == 1) {
          ((unsigned short*)Cp + boffC)[(size_t)(row + r) * N + col] = f2bf(v * scale);
        } else {
          ((float*)Cp + boffC)[(size_t)(row + r) * N + col] = v;
        }
      }
    }
  }
}

// ========== fused transposeV + softmax (both depend only on GEMM2) ==========
// blocks [0,16384): valsT[b][v][s] = values[b][s][v] (bf16), s-tiles clamped to
//   round64(vl) (GEMM3 never reads beyond). decode idx = x + 32y + 2048z.
// blocks [16384,32768): row softmax with valid_len masking, in place on bf16
//   scores; cols [vl, round64(vl)) get exact 0 (GEMM3 CLAMPK read range).
__global__ __launch_bounds__(256) void vtrans_softmax_kernel(
    const float* __restrict__ vals, unsigned short* __restrict__ valsT,
    unsigned short* __restrict__ scores, const int* __restrict__ valid_lens) {
  __shared__ float smem[32 * 33];
  const int bb = (int)blockIdx.x;
  const int tid = threadIdx.x;

  if (bb < 16384) {
    // ---- transpose+cast part: fp32 [2048][1024] -> bf16 [1024][2048] ----
    const int z = bb >> 11;
    const int r0 = ((bb >> 5) & 63) * 32;
    const int kEnd = (valid_lens[z] + 63) & ~63;
    if (r0 >= kEnd) return;
    const int c0 = (bb & 31) * 32;
    const int tx = tid & 31, ty = tid >> 5;  // (32,8)
    const float* inb = vals + (size_t)z * 2048 * 1024;
    unsigned short* outb = valsT + (size_t)z * 1024 * 2048;
#pragma unroll
    for (int k = 0; k < 4; ++k) {
      int r = ty + k * 8;
      smem[r * 33 + tx] = inb[(size_t)(r0 + r) * 1024 + c0 + tx];
    }
    __syncthreads();
#pragma unroll
    for (int k = 0; k < 4; ++k) {
      int c = ty + k * 8;
      outb[(size_t)(c0 + c) * 2048 + r0 + tx] = f2bf(smem[tx * 33 + c]);
    }
    return;
  }

  // ---- softmax part ----
  const int row = bb - 16384;
  const int b = row >> 11;  // LQ = 2048
  const int vl = valid_lens[b];
  const int kEnd = (vl + 63) & ~63;
  unsigned short* rp = scores + (size_t)row * LK_;
  const int wid = tid >> 6, lane = tid & 63;
  float* sred = smem;

  const int cb = tid * 8;
  const bool act = cb < kEnd;
  ushortx8 h = {};
  if (act) h = *(const ushortx8*)(rp + cb);
  float x[8];
#pragma unroll
  for (int t = 0; t < 8; ++t) x[t] = bf2f(h[t]);

  float m = -3.4e38f;
#pragma unroll
  for (int t = 0; t < 8; ++t)
    if (cb + t < vl) m = fmaxf(m, x[t]);
#pragma unroll
  for (int off = 32; off >= 1; off >>= 1) m = fmaxf(m, __shfl_xor(m, off));
  if (lane == 0) sred[wid] = m;
  __syncthreads();
  m = fmaxf(fmaxf(sred[0], sred[1]), fmaxf(sred[2], sred[3]));
  __syncthreads();

  float e[8];
  float s = 0.f;
#pragma unroll
  for (int t = 0; t < 8; ++t) {
    e[t] = (cb + t < vl) ? __expf(x[t] - m) : 0.f;
    s += e[t];
  }
#pragma unroll
  for (int off = 32; off >= 1; off >>= 1) s += __shfl_xor(s, off);
  if (lane == 0) sred[wid] = s;
  __syncthreads();
  s = sred[0] + sred[1] + sred[2] + sred[3];
  float inv = 1.f / s;

  if (act) {
    ushortx8 o;
#pragma unroll
    for (int t = 0; t < 8; ++t) o[t] = f2bf(e[t] * inv);
    *(ushortx8*)(rp + cb) = o;
  }
}

extern "C" void kernel_launch(void* const* d_in, const int* in_sizes, int n_in,
                              void* d_out, int out_size, void* d_ws, size_t ws_size,
                              hipStream_t stream) {
  const float* queries = (const float*)d_in[0];    // [8,2048,1024]
  const float* keys = (const float*)d_in[1];       // [8,2048,1024]
  const float* values = (const float*)d_in[2];     // [8,2048,1024]
  const int* valid_lens = (const int*)d_in[3];     // [8]
  const float* W_q = (const float*)d_in[4];        // [1024,1024]
  float* out = (float*)d_out;                      // [8,2048,1024] fp32

  // Re-association: scores = Q @ (K @ W^T)^T — project KEYS (maskable), not queries.
  // ws layout (ushort elems), total 81M = 162 MiB:
  //   q_bf    [0, 16M)      queries bf16
  //   scores  [16M, 48M)
  //   keysP   [48M, 64M)    K@W^T bf16; dead after GEMM2 -> valsT aliases it
  //   w_bf    [64M, 65M)    W_q bf16 row-major (= B^T operand as-is)
  //   keys_bf [65M, 81M)
  unsigned short* ws = (unsigned short*)d_ws;
  const size_t M1 = (size_t)1024 * 1024;
  unsigned short* q_bf = ws;
  unsigned short* scores = ws + 16 * M1;
  unsigned short* keysP = ws + 48 * M1;
  unsigned short* valsT = keysP;  // alias — transpose runs after GEMM2
  unsigned short* w_bf = ws + 64 * M1;
  unsigned short* keys_bf = ws + 65 * M1;

  // cast: keys (row-clamped to round256(vl)) + W_q. Queries cast is fused below.
  cast_kw_kernel<<<dim3(8704), 256, 0, stream>>>(
      keys, keys_bf, W_q, w_bf, valid_lens);
  // GEMM1': keysP[b] = keys_bf[b] @ W_q^T -> bf16 [2048,1024]; skip m-tiles >= vl.
  // Blocks [0,512): GEMM (8y x 8x x 8z, z-inner; ~288 alive on 768 slots).
  // Blocks [512,8704): queries fp32->bf16 cast backfilling the idle slots.
  gemm256x128_kernel<0, 0, 1, 0, 1><<<dim3(512 + 8192), 256, 0, stream>>>(
      keys_bf, w_bf, keysP, 2048, 1024, 1024,
      (long)2048 * 1024, 0, (long)2048 * 1024, 1.f, valid_lens, 3,
      queries, q_bf, 512);
  // GEMM2': scores = q_bf @ keysP^T / 32 -> bf16 [8][2048][2048]; cull masked n-tiles
  // grid: 8y x 16x x 8z, z-inner; ~544 alive on 768 slots -> single round
  gemm256x128_kernel<1, 1, 0, 0, 0><<<dim3(8 * 16 * 8), 256, 0, stream>>>(
      q_bf, keysP, scores, 2048, 2048, 1024,
      (long)2048 * 1024, (long)2048 * 1024, (long)2048 * 2048, 0.03125f, valid_lens, 4,
      nullptr, nullptr, 0);
  // fused: valsT transpose (clamped) + masked softmax — one launch, both post-GEMM2
  vtrans_softmax_kernel<<<dim3(32768), 256, 0, stream>>>(
      values, valsT, scores, valid_lens);
  // GEMM3: out = attn @ values (fp32 epilogue); K-loop clamped to valid_len
  // grid: 8y x 8x x 8z, z-inner (512 jobs on 768 slots; poles spread 3-deep)
  gemm256x128_kernel<2, 0, 0, 1, 0><<<dim3(8 * 8 * 8), 256, 0, stream>>>(
      scores, valsT, out, 2048, 1024, 2048,
      (long)2048 * 2048, (long)1024 * 2048, (long)2048 * 1024, 1.f, valid_lens, 3,
      nullptr, nullptr, 0);
}